// Round 13
// baseline (1241.524 us; speedup 1.0000x reference)
//
#include <hip/hip_runtime.h>

#define H 128
#define KV 256

typedef short bf16x8 __attribute__((ext_vector_type(8)));
typedef float f32x4 __attribute__((ext_vector_type(4)));
union FragU { uint4 u; bf16x8 s; };

__device__ __forceinline__ float bf2f(unsigned short u) {
  return __uint_as_float(((unsigned)u) << 16);
}
__device__ __forceinline__ unsigned short f2bf(float f) {
  unsigned b = __float_as_uint(f);
  b += 0x7FFFu + ((b >> 16) & 1u);   // round-to-nearest-even
  return (unsigned short)(b >> 16);
}
// rad6 = unique entries of the symmetric radial matrix [00,11,22,01,02,12]
__device__ __forceinline__ void rad6_from_cd(const float cd[9], float r6[6]) {
  r6[0] = cd[0]*cd[0] + cd[1]*cd[1] + cd[2]*cd[2];
  r6[1] = cd[3]*cd[3] + cd[4]*cd[4] + cd[5]*cd[5];
  r6[2] = cd[6]*cd[6] + cd[7]*cd[7] + cd[8]*cd[8];
  r6[3] = cd[0]*cd[3] + cd[1]*cd[4] + cd[2]*cd[5];
  r6[4] = cd[0]*cd[6] + cd[1]*cd[7] + cd[2]*cd[8];
  r6[5] = cd[3]*cd[6] + cd[4]*cd[7] + cd[5]*cd[8];
}
__constant__ int c_pa[6] = {0,4,8,1,2,5};
__constant__ int c_pb[6] = {0,0,0,3,6,7};

__global__ __launch_bounds__(256) void k_zero(float* __restrict__ p, int n) {
  int i = blockIdx.x * 256 + threadIdx.x;
  if (i < n) p[i] = 0.f;
}
__global__ __launch_bounds__(256) void k_sentinel(float* __restrict__ out, int n) {
  int i = blockIdx.x * 256 + threadIdx.x;
  if (i < n) out[i] = 1000.0f;
}

// pack Wc1 (128x512 fp32) into bf16 fragment order (verified R5-R12)
__global__ __launch_bounds__(256) void k_prep_w1(const float* __restrict__ Wc1,
                                                 uint4* __restrict__ w1f) {
  int t = blockIdx.x*256 + threadIdx.x;    // 8192 total
  int g = t >> 6, lane = t & 63;
  int q = g >> 5, kk = (g >> 3) & 3, mt = g & 7;
  int o = q*128 + mt*16 + (lane & 15);
  int kbase = kk*32 + (lane >> 4)*8;
  unsigned s[8];
  #pragma unroll
  for (int j = 0; j < 8; ++j) s[j] = f2bf(Wc1[(kbase+j)*512 + o]);
  uint4 u;
  u.x = s[0] | (s[1]<<16); u.y = s[2] | (s[3]<<16);
  u.z = s[4] | (s[5]<<16); u.w = s[6] | (s[7]<<16);
  w1f[g*64 + lane] = u;
}

// Wr6[6][512] = sym-folded (Wvo @ Wc1)
__global__ __launch_bounds__(256) void k_prep_wr6(const float* __restrict__ Wkv,
                                                  const float* __restrict__ Wc1,
                                                  float* __restrict__ Wr6) {
  int idx = blockIdx.x*256 + threadIdx.x;   // 3072
  if (idx >= 6*512) return;
  int d = idx >> 9, o = idx & 511;
  float s = 0.f;
  for (int k = 0; k < 128; ++k) {
    float w = Wkv[c_pa[d]*KV + 2*k + 1];
    if (d >= 3) w += Wkv[c_pb[d]*KV + 2*k + 1];
    s += w * Wc1[k*512 + o];
  }
  Wr6[d*512 + o] = s;
}

// ---------- dual counting sort (row + col) ----------
__global__ __launch_bounds__(256) void k_hist2(const int* __restrict__ row,
                                               const int* __restrict__ col,
                                               int* __restrict__ cr,
                                               int* __restrict__ cc, int E) {
  int e = blockIdx.x*256 + threadIdx.x;
  if (e >= E) return;
  atomicAdd(&cr[row[e]], 1);
  atomicAdd(&cc[col[e]], 1);
}

__global__ __launch_bounds__(1024) void k_scan2(
    const int* __restrict__ cr, int* __restrict__ rstart, int* __restrict__ rcur,
    const int* __restrict__ cc, int* __restrict__ cstart, int* __restrict__ ccur,
    int n) {
  const int* counts = (blockIdx.x == 0) ? cr : cc;
  int* start = (blockIdx.x == 0) ? rstart : cstart;
  int* cursor = (blockIdx.x == 0) ? rcur : ccur;
  __shared__ int wsum[16];
  __shared__ int carry_s;
  const int tid = threadIdx.x, lane = tid & 63, wid = tid >> 6;
  if (tid == 0) carry_s = 0;
  __syncthreads();
  for (int base = 0; base < n; base += 1024) {
    int i = base + tid;
    int v = (i < n) ? counts[i] : 0;
    int s = v;
    #pragma unroll
    for (int off = 1; off < 64; off <<= 1) {
      int t = __shfl_up(s, off, 64);
      if (lane >= off) s += t;
    }
    if (lane == 63) wsum[wid] = s;
    __syncthreads();
    if (wid == 0 && lane < 16) {
      int w = wsum[lane];
      #pragma unroll
      for (int off = 1; off < 16; off <<= 1) {
        int t = __shfl_up(w, off, 16);
        if (lane >= off) w += t;
      }
      wsum[lane] = w;
    }
    __syncthreads();
    int wexcl = (wid == 0) ? 0 : wsum[wid-1];
    int excl = carry_s + wexcl + (s - v);
    if (i < n) { start[i] = excl; cursor[i] = excl; }
    __syncthreads();
    if (tid == 0) carry_s += wsum[15];
    __syncthreads();
  }
  if (threadIdx.x == 0) start[n] = carry_s;
}

__global__ __launch_bounds__(256) void k_scatter2(
    const int* __restrict__ row, const int* __restrict__ col,
    int* __restrict__ rcur, int* __restrict__ eidx,
    int* __restrict__ ccur, int* __restrict__ eidx2, int E) {
  int e = blockIdx.x*256 + threadIdx.x;
  if (e >= E) return;
  int pos = atomicAdd(&rcur[row[e]], 1);
  eidx[pos] = e;
  int pos2 = atomicAdd(&ccur[col[e]], 1);
  eidx2[pos2] = e;
}

// ---------- K1: qn/kn fp32, vn bf16; 8 nodes/block ----------
__global__ __launch_bounds__(384) void k_node_proj(
    const float* __restrict__ h, const float* __restrict__ Wq,
    const float* __restrict__ bq, const float* __restrict__ Wkv,
    const float* __restrict__ bkv, float* __restrict__ qn,
    float* __restrict__ kn, unsigned short* __restrict__ vn, int N)
{
  __shared__ float hs[8][H];
  const int n0 = blockIdx.x * 8;
  const int t = threadIdx.x;
  for (int idx = t; idx < 8*H; idx += 384) {
    int nn = idx >> 7, jj = idx & 127;
    hs[nn][jj] = (n0 + nn < N) ? h[(size_t)(n0+nn)*H + jj] : 0.f;
  }
  __syncthreads();
  float a[8] = {0.f,0.f,0.f,0.f,0.f,0.f,0.f,0.f};
  if (t < H) {
    #pragma unroll 4
    for (int j = 0; j < H; ++j) {
      float w = Wq[j*H + t];
      #pragma unroll
      for (int k = 0; k < 8; ++k) a[k] += hs[k][j]*w;
    }
    float b = bq[t];
    #pragma unroll
    for (int k = 0; k < 8; ++k)
      if (n0+k < N) qn[(size_t)(n0+k)*H + t] = a[k] + b;
  } else {
    int c = t - H;
    #pragma unroll 4
    for (int j = 0; j < H; ++j) {
      float w = Wkv[(9 + j)*KV + c];
      #pragma unroll
      for (int k = 0; k < 8; ++k) a[k] += hs[k][j]*w;
    }
    float b = bkv[c];
    size_t ch = (size_t)(c >> 1);
    if (c & 1) {
      #pragma unroll
      for (int k = 0; k < 8; ++k)
        if (n0+k < N) vn[(size_t)(n0+k)*H + ch] = f2bf(a[k] + b);
    } else {
      #pragma unroll
      for (int k = 0; k < 8; ++k)
        if (n0+k < N) kn[(size_t)(n0+k)*H + ch] = a[k] + b;
    }
  }
}

// ---------- K2: fused per-row alpha + online softmax + h_out (verified R11/R12) ----------
__global__ __launch_bounds__(256) void k_row_fused(
    const float* __restrict__ h, const float* __restrict__ coord,
    const int* __restrict__ col, const float* __restrict__ Wkv,
    const int* __restrict__ row_start, const int* __restrict__ eidx,
    const float* __restrict__ qn, const float* __restrict__ kn,
    const unsigned* __restrict__ vnu, float* __restrict__ aout,
    float* __restrict__ hout, int N)
{
  __shared__ float wke6[6*128];
  __shared__ float wvo6[6*128];
  __shared__ float araw[4][64];
  const int tid = threadIdx.x;
  for (int idx = tid; idx < 6*128; idx += 256) {
    int d = idx >> 7, j = idx & 127;
    float we = Wkv[c_pa[d]*KV + 2*j];
    float wo = Wkv[c_pa[d]*KV + 2*j + 1];
    if (d >= 3) { we += Wkv[c_pb[d]*KV + 2*j]; wo += Wkv[c_pb[d]*KV + 2*j + 1]; }
    wke6[idx] = we; wvo6[idx] = wo;
  }
  __syncthreads();
  const int wid = tid >> 6, lane = tid & 63;
  const int r = blockIdx.x*4 + wid;
  if (r >= N) return;
  const int js = row_start[r], je = row_start[r+1];
  const int deg = je - js;
  float q0 = qn[(size_t)r*H + lane];
  float q1 = qn[(size_t)r*H + 64 + lane];
  float qw[6];
  #pragma unroll
  for (int d = 0; d < 6; ++d) {
    float p = q0*wke6[d*128 + lane] + q1*wke6[d*128 + 64 + lane];
    #pragma unroll
    for (int m = 32; m > 0; m >>= 1) p += __shfl_xor(p, m, 64);
    qw[d] = p;
  }
  float cr[9];
  #pragma unroll
  for (int i = 0; i < 9; ++i) cr[i] = coord[(size_t)r*9 + i];

  float m = -1e30f, l = 0.f, acc0 = 0.f, acc1 = 0.f;
  float t6[6] = {0.f,0.f,0.f,0.f,0.f,0.f};
  const bool big = (deg > 64);
  for (int base = js; base < je; base += 64) {
    int cnt = min(64, je - base);
    for (int t = 0; t < cnt; ++t) {
      int e = eidx[base + t];
      int c = col[e];
      float k0 = kn[(size_t)c*H + lane];
      float k1 = kn[(size_t)c*H + 64 + lane];
      unsigned v = vnu[(size_t)c*64 + lane];
      float cd[9], r6[6];
      #pragma unroll
      for (int i = 0; i < 9; ++i) cd[i] = cr[i] - coord[(size_t)c*9 + i];
      rad6_from_cd(cd, r6);
      float dot = q0*k0 + q1*k1;
      #pragma unroll
      for (int mm = 32; mm > 0; mm >>= 1) dot += __shfl_xor(dot, mm, 64);
      float ar = dot;
      #pragma unroll
      for (int d = 0; d < 6; ++d) ar += r6[d]*qw[d];
      float mn = fmaxf(m, ar);
      float scale = __expf(m - mn);
      float w = __expf(ar - mn);
      l = l*scale + w;
      acc0 = acc0*scale + w*__uint_as_float(v << 16);
      acc1 = acc1*scale + w*__uint_as_float(v & 0xffff0000u);
      #pragma unroll
      for (int d = 0; d < 6; ++d) t6[d] = t6[d]*scale + w*r6[d];
      m = mn;
      if (lane == 0) araw[wid][t] = ar;
    }
    if (big && lane < cnt) aout[eidx[base + lane]] = araw[wid][lane];  // raw spill
  }
  float invl = (deg > 0) ? 1.f/l : 0.f;
  float o0 = acc0, o1 = acc1;
  #pragma unroll
  for (int d = 0; d < 6; ++d) {
    o0 += t6[d]*wvo6[d*128 + 2*lane];
    o1 += t6[d]*wvo6[d*128 + 2*lane + 1];
  }
  hout[(size_t)r*H + 2*lane]     = h[(size_t)r*H + 2*lane]     + o0*invl;
  hout[(size_t)r*H + 2*lane + 1] = h[(size_t)r*H + 2*lane + 1] + o1*invl;
  if (!big) {
    if (lane < deg) aout[eidx[js + lane]] = __expf(araw[wid][lane] - m)*invl;
  } else {
    for (int j = js + lane; j < je; j += 64) {
      int e = eidx[j];
      aout[e] = __expf(aout[e] - m)*invl;
    }
  }
}

// ---------- K4a: hn[N][512] bf16 = vn @ Wc1 (node MFMA GEMM, verified R9-R12) ----------
__global__ __launch_bounds__(256) void k_node_hn(
    const unsigned* __restrict__ vnu, const uint4* __restrict__ w1f,
    unsigned short* __restrict__ hn, int N)
{
  __shared__ unsigned vt[128*64];
  __shared__ unsigned short hno[128*128];
  const int tid = threadIdx.x;
  const int wid = tid >> 6, lane = tid & 63;
  const int quad = lane >> 4, colc = lane & 15;
  const int n0 = blockIdx.x * 128;
  for (int i = 0; i < 32; ++i) {
    int el = i*4 + wid;
    int c = n0 + el; if (c >= N) c = N - 1;
    unsigned pk = vnu[(size_t)c*64 + lane];
    vt[el*64 + (((lane>>2) ^ (el&15))<<2) + (lane&3)] = pk;
  }
  __syncthreads();
  const int ntbase = wid*32;
  for (int q = 0; q < 4; ++q) {
    f32x4 acc[8][2];
    #pragma unroll
    for (int mt = 0; mt < 8; ++mt)
      #pragma unroll
      for (int nt = 0; nt < 2; ++nt) acc[mt][nt] = (f32x4){0.f,0.f,0.f,0.f};
    #pragma unroll
    for (int kk = 0; kk < 4; ++kk) {
      FragU bfr[2];
      #pragma unroll
      for (int nt = 0; nt < 2; ++nt) {
        int rrow = ntbase + nt*16 + colc;
        int chunk = kk*4 + quad;
        bfr[nt].u = *((const uint4*)&vt[rrow*64 + ((chunk ^ (rrow&15))<<2)]);
      }
      #pragma unroll
      for (int mt = 0; mt < 8; ++mt) {
        FragU afr;
        afr.u = w1f[(((q*4+kk)*8+mt)<<6) + lane];
        #pragma unroll
        for (int nt = 0; nt < 2; ++nt)
          acc[mt][nt] = __builtin_amdgcn_mfma_f32_16x16x32_bf16(
              afr.s, bfr[nt].s, acc[mt][nt], 0, 0, 0);
      }
    }
    #pragma unroll
    for (int mt = 0; mt < 8; ++mt)
      #pragma unroll
      for (int nt = 0; nt < 2; ++nt) {
        int node = ntbase + nt*16 + colc;
        int o = mt*16 + quad*4;
        unsigned lo = (unsigned)f2bf(acc[mt][nt][0]) | ((unsigned)f2bf(acc[mt][nt][1]) << 16);
        unsigned hi = (unsigned)f2bf(acc[mt][nt][2]) | ((unsigned)f2bf(acc[mt][nt][3]) << 16);
        *((uint2*)&hno[node*128 + o]) = make_uint2(lo, hi);
      }
    __syncthreads();
    const uint4* hns = (const uint4*)hno;
    #pragma unroll
    for (int it = 0; it < 8; ++it) {
      int u = it*256 + tid;
      int node = u >> 4, within = u & 15;
      int gn = n0 + node;
      if (gn < N) ((uint4*)hn)[(size_t)gn*64 + q*16 + within] = hns[node*16 + within];
    }
    __syncthreads();
  }
}

// ---------- K4b: wave-per-col MLP, jj-OUTER loop, 4-edge batches ----------
// Only 9 weight floats live at a time (6 wr6 + 3 wc2 per jj) -> no spill
// pressure; weight loads amortized over the 4-edge batch; hn[c] decoded once.
__global__ __launch_bounds__(256, 4) void k_edge_mlp4(
    const float* __restrict__ coord, const int* __restrict__ row,
    const float* __restrict__ Wr6, const float* __restrict__ Wc2,
    const uint4* __restrict__ hn4, const int* __restrict__ cstart,
    const int* __restrict__ eidx2, float* __restrict__ mlpout, int N)
{
  const int tid = threadIdx.x, wid = tid >> 6, lane = tid & 63;
  const int c = blockIdx.x*4 + wid;
  if (c >= N) return;
  const int js = cstart[c], je = cstart[c+1];
  if (js >= je) return;
  uint4 hh = hn4[(size_t)c*64 + lane];
  float hb[8];
  {
    unsigned uu[4] = {hh.x, hh.y, hh.z, hh.w};
    #pragma unroll
    for (int d = 0; d < 4; ++d) {
      hb[2*d]   = __uint_as_float(uu[d] << 16);
      hb[2*d+1] = __uint_as_float(uu[d] & 0xffff0000u);
    }
  }
  float cc[9];
  #pragma unroll
  for (int i = 0; i < 9; ++i) cc[i] = coord[(size_t)c*9 + i];
  const int ob = lane*8;
  for (int b = js; b < je; b += 4) {
    const int nb = je - b;             // >=1
    int e[4];
    float r6[4][6];
    #pragma unroll
    for (int k = 0; k < 4; ++k) {
      int jk = b + ((k < nb) ? k : 0);
      int ek = eidx2[jk];
      e[k] = ek;
      int r = row[ek];
      float cd[9];
      #pragma unroll
      for (int i = 0; i < 9; ++i) cd[i] = coord[(size_t)r*9 + i] - cc[i];
      rad6_from_cd(cd, r6[k]);
    }
    float cv[4][3];
    #pragma unroll
    for (int k = 0; k < 4; ++k) { cv[k][0]=0.f; cv[k][1]=0.f; cv[k][2]=0.f; }
    #pragma unroll
    for (int jj = 0; jj < 8; ++jj) {
      float w0 = Wr6[0*512 + ob + jj];
      float w1 = Wr6[1*512 + ob + jj];
      float w2 = Wr6[2*512 + ob + jj];
      float w3 = Wr6[3*512 + ob + jj];
      float w4 = Wr6[4*512 + ob + jj];
      float w5 = Wr6[5*512 + ob + jj];
      float wa = Wc2[(ob + jj)*3 + 0];
      float wb = Wc2[(ob + jj)*3 + 1];
      float wc = Wc2[(ob + jj)*3 + 2];
      float hjj = hb[jj];
      #pragma unroll
      for (int k = 0; k < 4; ++k) {
        float s = hjj + r6[k][0]*w0 + r6[k][1]*w1 + r6[k][2]*w2
                      + r6[k][3]*w3 + r6[k][4]*w4 + r6[k][5]*w5;
        s = s / (1.f + __expf(-s));    // silu
        cv[k][0] += s*wa; cv[k][1] += s*wb; cv[k][2] += s*wc;
      }
    }
    #pragma unroll
    for (int k = 0; k < 4; ++k) {
      #pragma unroll
      for (int m = 32; m > 0; m >>= 1) {
        cv[k][0] += __shfl_xor(cv[k][0], m, 64);
        cv[k][1] += __shfl_xor(cv[k][1], m, 64);
        cv[k][2] += __shfl_xor(cv[k][2], m, 64);
      }
      if (lane == 0 && k < nb) {
        float* mp = &mlpout[(size_t)e[k]*3];
        mp[0] = cv[k][0]; mp[1] = cv[k][1]; mp[2] = cv[k][2];
      }
    }
  }
}

// ---------- K5: coord_out (wave per row, lane per edge) ----------
__global__ __launch_bounds__(256) void k_coord(
    const float* __restrict__ coord, const int* __restrict__ col,
    const int* __restrict__ row_start, const int* __restrict__ eidx,
    const float* __restrict__ aout, const float* __restrict__ mlpout,
    float* __restrict__ cout, int N)
{
  const int tid = threadIdx.x;
  const int wid = tid >> 6, lane = tid & 63;
  const int r = blockIdx.x*4 + wid;
  if (r >= N) return;
  const int js = row_start[r], je = row_start[r+1];
  float cr[9];
  #pragma unroll
  for (int i = 0; i < 9; ++i) cr[i] = coord[(size_t)r*9 + i];
  float cg[9] = {0.f,0.f,0.f,0.f,0.f,0.f,0.f,0.f,0.f};
  for (int j = js + lane; j < je; j += 64) {
    int e = eidx[j];
    float a = aout[e];
    int c = col[e];
    float cd[9];
    #pragma unroll
    for (int i = 0; i < 9; ++i) cd[i] = cr[i] - coord[(size_t)c*9 + i];
    float p0 = a*mlpout[(size_t)e*3+0];
    float p1 = a*mlpout[(size_t)e*3+1];
    float p2 = a*mlpout[(size_t)e*3+2];
    #pragma unroll
    for (int d = 0; d < 3; ++d) {
      cg[0+d] += p0*cd[0+d];
      cg[3+d] += p1*cd[3+d];
      cg[6+d] += p2*cd[6+d];
    }
  }
  #pragma unroll
  for (int i = 0; i < 9; ++i)
    #pragma unroll
    for (int m = 32; m > 0; m >>= 1) cg[i] += __shfl_xor(cg[i], m, 64);
  if (lane == 0) {
    #pragma unroll
    for (int i = 0; i < 9; ++i) {
      float x = fminf(10.f, fmaxf(-10.f, cg[i]));
      cout[(size_t)r*9 + i] = cr[i] + x;
    }
  }
}

extern "C" void kernel_launch(void* const* d_in, const int* in_sizes, int n_in,
                              void* d_out, int out_size, void* d_ws, size_t ws_size,
                              hipStream_t stream)
{
  const float* h     = (const float*)d_in[0];
  const float* coord = (const float*)d_in[1];
  const int* row = (const int*)d_in[2];
  const int* col = (const int*)d_in[3];
  const float* Wq  = (const float*)d_in[4];
  const float* bq  = (const float*)d_in[5];
  const float* Wkv = (const float*)d_in[6];
  const float* bkv = (const float*)d_in[7];
  const float* Wc1 = (const float*)d_in[8];
  const float* Wc2 = (const float*)d_in[9];
  const int N = in_sizes[0] / H;
  const int E = in_sizes[2];
  float* out = (float*)d_out;

  // layout: [qn|kn fp32] (dead after k_row_fused) <- hn bf16 aliases
  char* p = (char*)d_ws;
  float* qn = (float*)p;
  float* kn = (float*)(p + (size_t)N*H*4);
  unsigned short* hn = (unsigned short*)p;
  p += (size_t)N*H*8;
  unsigned short* vn = (unsigned short*)p;  p += (size_t)N*H*2;
  float* mlpout = (float*)p;                p += (size_t)E*3*4;
  int* counts_r = (int*)p;                  p += (size_t)N*4;
  int* counts_c = (int*)p;                  p += (size_t)N*4;   // adjacent: one zero
  int* row_start = (int*)p;                 p += (size_t)(N+1)*4;
  int* cursor_r = (int*)p;                  p += (size_t)N*4;
  int* cstart = (int*)p;                    p += (size_t)(N+1)*4;
  int* cursor_c = (int*)p;                  p += (size_t)N*4;
  int* eidx = (int*)p;                      p += (size_t)E*4;
  int* eidx2 = (int*)p;                     p += (size_t)E*4;
  uint4* w1f = (uint4*)((((size_t)p) + 15) & ~(size_t)15);
  float* Wr6 = (float*)((char*)w1f + 8192*16);
  const size_t need = (size_t)((char*)Wr6 + 6*512*4 - (char*)d_ws);

  if (ws_size < need) {
    k_sentinel<<<(out_size + 255)/256, 256, 0, stream>>>(out, out_size);
    return;
  }

  float* hout = out;
  float* cout = out + (size_t)N*H;
  float* aout = cout + (size_t)N*9;   // normalized alpha (edge order)

  k_zero<<<(2*N + 255)/256, 256, 0, stream>>>((float*)counts_r, 2*N);
  k_prep_w1<<<32, 256, 0, stream>>>(Wc1, w1f);
  k_prep_wr6<<<12, 256, 0, stream>>>(Wkv, Wc1, Wr6);
  k_hist2<<<(E + 255)/256, 256, 0, stream>>>(row, col, counts_r, counts_c, E);
  k_node_proj<<<(N + 7)/8, 384, 0, stream>>>(h, Wq, bq, Wkv, bkv, qn, kn, vn, N);
  k_scan2<<<2, 1024, 0, stream>>>(counts_r, row_start, cursor_r,
                                  counts_c, cstart, cursor_c, N);
  k_scatter2<<<(E + 255)/256, 256, 0, stream>>>(row, col, cursor_r, eidx,
                                                cursor_c, eidx2, E);
  k_row_fused<<<(N + 3)/4, 256, 0, stream>>>(h, coord, col, Wkv, row_start, eidx,
                                             qn, kn, (const unsigned*)vn, aout,
                                             hout, N);
  // qn/kn dead from here: hn overwrites their region
  k_node_hn<<<(N + 127)/128, 256, 0, stream>>>((const unsigned*)vn, w1f, hn, N);
  k_edge_mlp4<<<(N + 3)/4, 256, 0, stream>>>(coord, row, Wr6, Wc2,
                                             (const uint4*)hn, cstart, eidx2,
                                             mlpout, N);
  k_coord<<<(N + 3)/4, 256, 0, stream>>>(coord, col, row_start, eidx, aout,
                                         mlpout, cout, N);
}

// Round 14
// 969.735 us; speedup vs baseline: 1.2803x; 1.2803x over previous
//
#include <hip/hip_runtime.h>

#define H 128
#define KV 256

typedef short bf16x8 __attribute__((ext_vector_type(8)));
typedef float f32x4 __attribute__((ext_vector_type(4)));
union FragU { uint4 u; bf16x8 s; };

__device__ __forceinline__ float bf2f(unsigned short u) {
  return __uint_as_float(((unsigned)u) << 16);
}
__device__ __forceinline__ unsigned short f2bf(float f) {
  unsigned b = __float_as_uint(f);
  b += 0x7FFFu + ((b >> 16) & 1u);   // round-to-nearest-even
  return (unsigned short)(b >> 16);
}
// rad6 = unique entries of the symmetric radial matrix [00,11,22,01,02,12]
__device__ __forceinline__ void rad6_from_cd(const float cd[9], float r6[6]) {
  r6[0] = cd[0]*cd[0] + cd[1]*cd[1] + cd[2]*cd[2];
  r6[1] = cd[3]*cd[3] + cd[4]*cd[4] + cd[5]*cd[5];
  r6[2] = cd[6]*cd[6] + cd[7]*cd[7] + cd[8]*cd[8];
  r6[3] = cd[0]*cd[3] + cd[1]*cd[4] + cd[2]*cd[5];
  r6[4] = cd[0]*cd[6] + cd[1]*cd[7] + cd[2]*cd[8];
  r6[5] = cd[3]*cd[6] + cd[4]*cd[7] + cd[5]*cd[8];
}
__constant__ int c_pa[6] = {0,4,8,1,2,5};
__constant__ int c_pb[6] = {0,0,0,3,6,7};

__global__ __launch_bounds__(256) void k_zero(float* __restrict__ p, int n) {
  int i = blockIdx.x * 256 + threadIdx.x;
  if (i < n) p[i] = 0.f;
}
__global__ __launch_bounds__(256) void k_sentinel(float* __restrict__ out, int n) {
  int i = blockIdx.x * 256 + threadIdx.x;
  if (i < n) out[i] = 1000.0f;
}

// pack Wc1 (128x512 fp32) into bf16 fragment order (verified R5-R13)
__global__ __launch_bounds__(256) void k_prep_w1(const float* __restrict__ Wc1,
                                                 uint4* __restrict__ w1f) {
  int t = blockIdx.x*256 + threadIdx.x;    // 8192 total
  int g = t >> 6, lane = t & 63;
  int q = g >> 5, kk = (g >> 3) & 3, mt = g & 7;
  int o = q*128 + mt*16 + (lane & 15);
  int kbase = kk*32 + (lane >> 4)*8;
  unsigned s[8];
  #pragma unroll
  for (int j = 0; j < 8; ++j) s[j] = f2bf(Wc1[(kbase+j)*512 + o]);
  uint4 u;
  u.x = s[0] | (s[1]<<16); u.y = s[2] | (s[3]<<16);
  u.z = s[4] | (s[5]<<16); u.w = s[6] | (s[7]<<16);
  w1f[g*64 + lane] = u;
}

// Wr6[6][512] = sym-folded (Wvo @ Wc1)
__global__ __launch_bounds__(256) void k_prep_wr6(const float* __restrict__ Wkv,
                                                  const float* __restrict__ Wc1,
                                                  float* __restrict__ Wr6) {
  int idx = blockIdx.x*256 + threadIdx.x;   // 3072
  if (idx >= 6*512) return;
  int d = idx >> 9, o = idx & 511;
  float s = 0.f;
  for (int k = 0; k < 128; ++k) {
    float w = Wkv[c_pa[d]*KV + 2*k + 1];
    if (d >= 3) w += Wkv[c_pb[d]*KV + 2*k + 1];
    s += w * Wc1[k*512 + o];
  }
  Wr6[d*512 + o] = s;
}

// ---------- dual counting sort (row + col) ----------
__global__ __launch_bounds__(256) void k_hist2(const int* __restrict__ row,
                                               const int* __restrict__ col,
                                               int* __restrict__ cr,
                                               int* __restrict__ cc, int E) {
  int e = blockIdx.x*256 + threadIdx.x;
  if (e >= E) return;
  atomicAdd(&cr[row[e]], 1);
  atomicAdd(&cc[col[e]], 1);
}

__global__ __launch_bounds__(1024) void k_scan2(
    const int* __restrict__ cr, int* __restrict__ rstart, int* __restrict__ rcur,
    const int* __restrict__ cc, int* __restrict__ cstart, int* __restrict__ ccur,
    int n) {
  const int* counts = (blockIdx.x == 0) ? cr : cc;
  int* start = (blockIdx.x == 0) ? rstart : cstart;
  int* cursor = (blockIdx.x == 0) ? rcur : ccur;
  __shared__ int wsum[16];
  __shared__ int carry_s;
  const int tid = threadIdx.x, lane = tid & 63, wid = tid >> 6;
  if (tid == 0) carry_s = 0;
  __syncthreads();
  for (int base = 0; base < n; base += 1024) {
    int i = base + tid;
    int v = (i < n) ? counts[i] : 0;
    int s = v;
    #pragma unroll
    for (int off = 1; off < 64; off <<= 1) {
      int t = __shfl_up(s, off, 64);
      if (lane >= off) s += t;
    }
    if (lane == 63) wsum[wid] = s;
    __syncthreads();
    if (wid == 0 && lane < 16) {
      int w = wsum[lane];
      #pragma unroll
      for (int off = 1; off < 16; off <<= 1) {
        int t = __shfl_up(w, off, 16);
        if (lane >= off) w += t;
      }
      wsum[lane] = w;
    }
    __syncthreads();
    int wexcl = (wid == 0) ? 0 : wsum[wid-1];
    int excl = carry_s + wexcl + (s - v);
    if (i < n) { start[i] = excl; cursor[i] = excl; }
    __syncthreads();
    if (tid == 0) carry_s += wsum[15];
    __syncthreads();
  }
  if (threadIdx.x == 0) start[n] = carry_s;
}

__global__ __launch_bounds__(256) void k_scatter2(
    const int* __restrict__ row, const int* __restrict__ col,
    int* __restrict__ rcur, int* __restrict__ eidx,
    int* __restrict__ ccur, int* __restrict__ eidx2, int E) {
  int e = blockIdx.x*256 + threadIdx.x;
  if (e >= E) return;
  int pos = atomicAdd(&rcur[row[e]], 1);
  eidx[pos] = e;
  int pos2 = atomicAdd(&ccur[col[e]], 1);
  eidx2[pos2] = e;
}

// ---------- K1: qn/kn fp32, vn bf16; 8 nodes/block ----------
__global__ __launch_bounds__(384) void k_node_proj(
    const float* __restrict__ h, const float* __restrict__ Wq,
    const float* __restrict__ bq, const float* __restrict__ Wkv,
    const float* __restrict__ bkv, float* __restrict__ qn,
    float* __restrict__ kn, unsigned short* __restrict__ vn, int N)
{
  __shared__ float hs[8][H];
  const int n0 = blockIdx.x * 8;
  const int t = threadIdx.x;
  for (int idx = t; idx < 8*H; idx += 384) {
    int nn = idx >> 7, jj = idx & 127;
    hs[nn][jj] = (n0 + nn < N) ? h[(size_t)(n0+nn)*H + jj] : 0.f;
  }
  __syncthreads();
  float a[8] = {0.f,0.f,0.f,0.f,0.f,0.f,0.f,0.f};
  if (t < H) {
    #pragma unroll 4
    for (int j = 0; j < H; ++j) {
      float w = Wq[j*H + t];
      #pragma unroll
      for (int k = 0; k < 8; ++k) a[k] += hs[k][j]*w;
    }
    float b = bq[t];
    #pragma unroll
    for (int k = 0; k < 8; ++k)
      if (n0+k < N) qn[(size_t)(n0+k)*H + t] = a[k] + b;
  } else {
    int c = t - H;
    #pragma unroll 4
    for (int j = 0; j < H; ++j) {
      float w = Wkv[(9 + j)*KV + c];
      #pragma unroll
      for (int k = 0; k < 8; ++k) a[k] += hs[k][j]*w;
    }
    float b = bkv[c];
    size_t ch = (size_t)(c >> 1);
    if (c & 1) {
      #pragma unroll
      for (int k = 0; k < 8; ++k)
        if (n0+k < N) vn[(size_t)(n0+k)*H + ch] = f2bf(a[k] + b);
    } else {
      #pragma unroll
      for (int k = 0; k < 8; ++k)
        if (n0+k < N) kn[(size_t)(n0+k)*H + ch] = a[k] + b;
    }
  }
}

// ---------- K2: fused per-row alpha + online softmax + h_out (verified R11-R13) ----------
__global__ __launch_bounds__(256) void k_row_fused(
    const float* __restrict__ h, const float* __restrict__ coord,
    const int* __restrict__ col, const float* __restrict__ Wkv,
    const int* __restrict__ row_start, const int* __restrict__ eidx,
    const float* __restrict__ qn, const float* __restrict__ kn,
    const unsigned* __restrict__ vnu, float* __restrict__ aout,
    float* __restrict__ hout, int N)
{
  __shared__ float wke6[6*128];
  __shared__ float wvo6[6*128];
  __shared__ float araw[4][64];
  const int tid = threadIdx.x;
  for (int idx = tid; idx < 6*128; idx += 256) {
    int d = idx >> 7, j = idx & 127;
    float we = Wkv[c_pa[d]*KV + 2*j];
    float wo = Wkv[c_pa[d]*KV + 2*j + 1];
    if (d >= 3) { we += Wkv[c_pb[d]*KV + 2*j]; wo += Wkv[c_pb[d]*KV + 2*j + 1]; }
    wke6[idx] = we; wvo6[idx] = wo;
  }
  __syncthreads();
  const int wid = tid >> 6, lane = tid & 63;
  const int r = blockIdx.x*4 + wid;
  if (r >= N) return;
  const int js = row_start[r], je = row_start[r+1];
  const int deg = je - js;
  float q0 = qn[(size_t)r*H + lane];
  float q1 = qn[(size_t)r*H + 64 + lane];
  float qw[6];
  #pragma unroll
  for (int d = 0; d < 6; ++d) {
    float p = q0*wke6[d*128 + lane] + q1*wke6[d*128 + 64 + lane];
    #pragma unroll
    for (int m = 32; m > 0; m >>= 1) p += __shfl_xor(p, m, 64);
    qw[d] = p;
  }
  float cr[9];
  #pragma unroll
  for (int i = 0; i < 9; ++i) cr[i] = coord[(size_t)r*9 + i];

  float m = -1e30f, l = 0.f, acc0 = 0.f, acc1 = 0.f;
  float t6[6] = {0.f,0.f,0.f,0.f,0.f,0.f};
  const bool big = (deg > 64);
  for (int base = js; base < je; base += 64) {
    int cnt = min(64, je - base);
    for (int t = 0; t < cnt; ++t) {
      int e = eidx[base + t];
      int c = col[e];
      float k0 = kn[(size_t)c*H + lane];
      float k1 = kn[(size_t)c*H + 64 + lane];
      unsigned v = vnu[(size_t)c*64 + lane];
      float cd[9], r6[6];
      #pragma unroll
      for (int i = 0; i < 9; ++i) cd[i] = cr[i] - coord[(size_t)c*9 + i];
      rad6_from_cd(cd, r6);
      float dot = q0*k0 + q1*k1;
      #pragma unroll
      for (int mm = 32; mm > 0; mm >>= 1) dot += __shfl_xor(dot, mm, 64);
      float ar = dot;
      #pragma unroll
      for (int d = 0; d < 6; ++d) ar += r6[d]*qw[d];
      float mn = fmaxf(m, ar);
      float scale = __expf(m - mn);
      float w = __expf(ar - mn);
      l = l*scale + w;
      acc0 = acc0*scale + w*__uint_as_float(v << 16);
      acc1 = acc1*scale + w*__uint_as_float(v & 0xffff0000u);
      #pragma unroll
      for (int d = 0; d < 6; ++d) t6[d] = t6[d]*scale + w*r6[d];
      m = mn;
      if (lane == 0) araw[wid][t] = ar;
    }
    if (big && lane < cnt) aout[eidx[base + lane]] = araw[wid][lane];  // raw spill
  }
  float invl = (deg > 0) ? 1.f/l : 0.f;
  float o0 = acc0, o1 = acc1;
  #pragma unroll
  for (int d = 0; d < 6; ++d) {
    o0 += t6[d]*wvo6[d*128 + 2*lane];
    o1 += t6[d]*wvo6[d*128 + 2*lane + 1];
  }
  hout[(size_t)r*H + 2*lane]     = h[(size_t)r*H + 2*lane]     + o0*invl;
  hout[(size_t)r*H + 2*lane + 1] = h[(size_t)r*H + 2*lane + 1] + o1*invl;
  if (!big) {
    if (lane < deg) aout[eidx[js + lane]] = __expf(araw[wid][lane] - m)*invl;
  } else {
    for (int j = js + lane; j < je; j += 64) {
      int e = eidx[j];
      aout[e] = __expf(aout[e] - m)*invl;
    }
  }
}

// ---------- K4a: hn[N][512] bf16 = vn @ Wc1 (node MFMA GEMM, verified R9-R13) ----------
__global__ __launch_bounds__(256) void k_node_hn(
    const unsigned* __restrict__ vnu, const uint4* __restrict__ w1f,
    unsigned short* __restrict__ hn, int N)
{
  __shared__ unsigned vt[128*64];
  __shared__ unsigned short hno[128*128];
  const int tid = threadIdx.x;
  const int wid = tid >> 6, lane = tid & 63;
  const int quad = lane >> 4, colc = lane & 15;
  const int n0 = blockIdx.x * 128;
  for (int i = 0; i < 32; ++i) {
    int el = i*4 + wid;
    int c = n0 + el; if (c >= N) c = N - 1;
    unsigned pk = vnu[(size_t)c*64 + lane];
    vt[el*64 + (((lane>>2) ^ (el&15))<<2) + (lane&3)] = pk;
  }
  __syncthreads();
  const int ntbase = wid*32;
  for (int q = 0; q < 4; ++q) {
    f32x4 acc[8][2];
    #pragma unroll
    for (int mt = 0; mt < 8; ++mt)
      #pragma unroll
      for (int nt = 0; nt < 2; ++nt) acc[mt][nt] = (f32x4){0.f,0.f,0.f,0.f};
    #pragma unroll
    for (int kk = 0; kk < 4; ++kk) {
      FragU bfr[2];
      #pragma unroll
      for (int nt = 0; nt < 2; ++nt) {
        int rrow = ntbase + nt*16 + colc;
        int chunk = kk*4 + quad;
        bfr[nt].u = *((const uint4*)&vt[rrow*64 + ((chunk ^ (rrow&15))<<2)]);
      }
      #pragma unroll
      for (int mt = 0; mt < 8; ++mt) {
        FragU afr;
        afr.u = w1f[(((q*4+kk)*8+mt)<<6) + lane];
        #pragma unroll
        for (int nt = 0; nt < 2; ++nt)
          acc[mt][nt] = __builtin_amdgcn_mfma_f32_16x16x32_bf16(
              afr.s, bfr[nt].s, acc[mt][nt], 0, 0, 0);
      }
    }
    #pragma unroll
    for (int mt = 0; mt < 8; ++mt)
      #pragma unroll
      for (int nt = 0; nt < 2; ++nt) {
        int node = ntbase + nt*16 + colc;
        int o = mt*16 + quad*4;
        unsigned lo = (unsigned)f2bf(acc[mt][nt][0]) | ((unsigned)f2bf(acc[mt][nt][1]) << 16);
        unsigned hi = (unsigned)f2bf(acc[mt][nt][2]) | ((unsigned)f2bf(acc[mt][nt][3]) << 16);
        *((uint2*)&hno[node*128 + o]) = make_uint2(lo, hi);
      }
    __syncthreads();
    const uint4* hns = (const uint4*)hno;
    #pragma unroll
    for (int it = 0; it < 8; ++it) {
      int u = it*256 + tid;
      int node = u >> 4, within = u & 15;
      int gn = n0 + node;
      if (gn < N) ((uint4*)hn)[(size_t)gn*64 + q*16 + within] = hns[node*16 + within];
    }
    __syncthreads();
  }
}

// ---------- K4b: wave-per-edge MLP, weights in LDS, batch 2, jj-outer ----------
// wlds[jj][lane][9]: stride 9 dwords -> (lane*9+f) mod 32 is 2-lanes/bank = free.
// Live regs ~50 (< the allocator's 64 ceiling) -> no spill possible.
__global__ __launch_bounds__(256) void k_edge_mlp5(
    const float* __restrict__ coord, const int* __restrict__ row,
    const int* __restrict__ col, const float* __restrict__ Wr6,
    const float* __restrict__ Wc2, const uint4* __restrict__ hn4,
    const int* __restrict__ eidx2, float* __restrict__ mlpout, int E)
{
  __shared__ float wlds[8*64*9];   // 18KB
  const int tid = threadIdx.x, wid = tid >> 6, lane = tid & 63;
  for (int idx = tid; idx < 8*64*9; idx += 256) {
    int jl = idx / 9, f = idx - jl*9;
    int jj = jl >> 6, ln = jl & 63;
    int o = ln*8 + jj;
    wlds[idx] = (f < 6) ? Wr6[f*512 + o] : Wc2[o*3 + (f - 6)];
  }
  __syncthreads();
  int gw = blockIdx.x*4 + wid;
  int nw = gridDim.x*4;
  int chunk = (E + nw - 1)/nw;
  int j0 = gw*chunk, j1 = min(E, j0 + chunk);
  const int lb = lane*9;           // wlds lane base within a jj-slab
  for (int j = j0; j < j1; j += 2) {
    const int nb = j1 - j;         // >=1
    int e0 = eidx2[j];
    int e1 = (nb > 1) ? eidx2[j+1] : e0;
    int c0 = col[e0], c1 = col[e1];
    uint4 h0 = hn4[(size_t)c0*64 + lane];
    uint4 h1 = hn4[(size_t)c1*64 + lane];
    float r60[6], r61[6];
    {
      int r = row[e0];
      float cd[9];
      #pragma unroll
      for (int i = 0; i < 9; ++i) cd[i] = coord[(size_t)r*9+i] - coord[(size_t)c0*9+i];
      rad6_from_cd(cd, r60);
    }
    {
      int r = row[e1];
      float cd[9];
      #pragma unroll
      for (int i = 0; i < 9; ++i) cd[i] = coord[(size_t)r*9+i] - coord[(size_t)c1*9+i];
      rad6_from_cd(cd, r61);
    }
    float cv0[3] = {0.f,0.f,0.f}, cv1[3] = {0.f,0.f,0.f};
    unsigned u0[4] = {h0.x, h0.y, h0.z, h0.w};
    unsigned u1[4] = {h1.x, h1.y, h1.z, h1.w};
    #pragma unroll
    for (int jj = 0; jj < 8; ++jj) {
      const float* w = &wlds[jj*576 + lb];
      float hb0 = (jj & 1) ? __uint_as_float(u0[jj>>1] & 0xffff0000u)
                           : __uint_as_float(u0[jj>>1] << 16);
      float hb1 = (jj & 1) ? __uint_as_float(u1[jj>>1] & 0xffff0000u)
                           : __uint_as_float(u1[jj>>1] << 16);
      float s0 = hb0 + r60[0]*w[0] + r60[1]*w[1] + r60[2]*w[2]
                     + r60[3]*w[3] + r60[4]*w[4] + r60[5]*w[5];
      float s1 = hb1 + r61[0]*w[0] + r61[1]*w[1] + r61[2]*w[2]
                     + r61[3]*w[3] + r61[4]*w[4] + r61[5]*w[5];
      s0 = s0 / (1.f + __expf(-s0));   // silu
      s1 = s1 / (1.f + __expf(-s1));
      cv0[0] += s0*w[6]; cv0[1] += s0*w[7]; cv0[2] += s0*w[8];
      cv1[0] += s1*w[6]; cv1[1] += s1*w[7]; cv1[2] += s1*w[8];
    }
    #pragma unroll
    for (int m = 32; m > 0; m >>= 1) {
      cv0[0] += __shfl_xor(cv0[0], m, 64);
      cv0[1] += __shfl_xor(cv0[1], m, 64);
      cv0[2] += __shfl_xor(cv0[2], m, 64);
      cv1[0] += __shfl_xor(cv1[0], m, 64);
      cv1[1] += __shfl_xor(cv1[1], m, 64);
      cv1[2] += __shfl_xor(cv1[2], m, 64);
    }
    if (lane == 0) {
      float* mp0 = &mlpout[(size_t)e0*3];
      mp0[0] = cv0[0]; mp0[1] = cv0[1]; mp0[2] = cv0[2];
      if (nb > 1) {
        float* mp1 = &mlpout[(size_t)e1*3];
        mp1[0] = cv1[0]; mp1[1] = cv1[1]; mp1[2] = cv1[2];
      }
    }
  }
}

// ---------- K5: coord_out (wave per row, lane per edge) ----------
__global__ __launch_bounds__(256) void k_coord(
    const float* __restrict__ coord, const int* __restrict__ col,
    const int* __restrict__ row_start, const int* __restrict__ eidx,
    const float* __restrict__ aout, const float* __restrict__ mlpout,
    float* __restrict__ cout, int N)
{
  const int tid = threadIdx.x;
  const int wid = tid >> 6, lane = tid & 63;
  const int r = blockIdx.x*4 + wid;
  if (r >= N) return;
  const int js = row_start[r], je = row_start[r+1];
  float cr[9];
  #pragma unroll
  for (int i = 0; i < 9; ++i) cr[i] = coord[(size_t)r*9 + i];
  float cg[9] = {0.f,0.f,0.f,0.f,0.f,0.f,0.f,0.f,0.f};
  for (int j = js + lane; j < je; j += 64) {
    int e = eidx[j];
    float a = aout[e];
    int c = col[e];
    float cd[9];
    #pragma unroll
    for (int i = 0; i < 9; ++i) cd[i] = cr[i] - coord[(size_t)c*9 + i];
    float p0 = a*mlpout[(size_t)e*3+0];
    float p1 = a*mlpout[(size_t)e*3+1];
    float p2 = a*mlpout[(size_t)e*3+2];
    #pragma unroll
    for (int d = 0; d < 3; ++d) {
      cg[0+d] += p0*cd[0+d];
      cg[3+d] += p1*cd[3+d];
      cg[6+d] += p2*cd[6+d];
    }
  }
  #pragma unroll
  for (int i = 0; i < 9; ++i)
    #pragma unroll
    for (int m = 32; m > 0; m >>= 1) cg[i] += __shfl_xor(cg[i], m, 64);
  if (lane == 0) {
    #pragma unroll
    for (int i = 0; i < 9; ++i) {
      float x = fminf(10.f, fmaxf(-10.f, cg[i]));
      cout[(size_t)r*9 + i] = cr[i] + x;
    }
  }
}

extern "C" void kernel_launch(void* const* d_in, const int* in_sizes, int n_in,
                              void* d_out, int out_size, void* d_ws, size_t ws_size,
                              hipStream_t stream)
{
  const float* h     = (const float*)d_in[0];
  const float* coord = (const float*)d_in[1];
  const int* row = (const int*)d_in[2];
  const int* col = (const int*)d_in[3];
  const float* Wq  = (const float*)d_in[4];
  const float* bq  = (const float*)d_in[5];
  const float* Wkv = (const float*)d_in[6];
  const float* bkv = (const float*)d_in[7];
  const float* Wc1 = (const float*)d_in[8];
  const float* Wc2 = (const float*)d_in[9];
  const int N = in_sizes[0] / H;
  const int E = in_sizes[2];
  float* out = (float*)d_out;

  // layout: [qn|kn fp32] (dead after k_row_fused) <- hn bf16 aliases
  char* p = (char*)d_ws;
  float* qn = (float*)p;
  float* kn = (float*)(p + (size_t)N*H*4);
  unsigned short* hn = (unsigned short*)p;
  p += (size_t)N*H*8;
  unsigned short* vn = (unsigned short*)p;  p += (size_t)N*H*2;
  float* mlpout = (float*)p;                p += (size_t)E*3*4;
  int* counts_r = (int*)p;                  p += (size_t)N*4;
  int* counts_c = (int*)p;                  p += (size_t)N*4;   // adjacent: one zero
  int* row_start = (int*)p;                 p += (size_t)(N+1)*4;
  int* cursor_r = (int*)p;                  p += (size_t)N*4;
  int* cstart = (int*)p;                    p += (size_t)(N+1)*4;
  int* cursor_c = (int*)p;                  p += (size_t)N*4;
  int* eidx = (int*)p;                      p += (size_t)E*4;
  int* eidx2 = (int*)p;                     p += (size_t)E*4;
  uint4* w1f = (uint4*)((((size_t)p) + 15) & ~(size_t)15);
  float* Wr6 = (float*)((char*)w1f + 8192*16);
  const size_t need = (size_t)((char*)Wr6 + 6*512*4 - (char*)d_ws);

  if (ws_size < need) {
    k_sentinel<<<(out_size + 255)/256, 256, 0, stream>>>(out, out_size);
    return;
  }

  float* hout = out;
  float* cout = out + (size_t)N*H;
  float* aout = cout + (size_t)N*9;   // normalized alpha (edge order)

  k_zero<<<(2*N + 255)/256, 256, 0, stream>>>((float*)counts_r, 2*N);
  k_prep_w1<<<32, 256, 0, stream>>>(Wc1, w1f);
  k_prep_wr6<<<12, 256, 0, stream>>>(Wkv, Wc1, Wr6);
  k_hist2<<<(E + 255)/256, 256, 0, stream>>>(row, col, counts_r, counts_c, E);
  k_node_proj<<<(N + 7)/8, 384, 0, stream>>>(h, Wq, bq, Wkv, bkv, qn, kn, vn, N);
  k_scan2<<<2, 1024, 0, stream>>>(counts_r, row_start, cursor_r,
                                  counts_c, cstart, cursor_c, N);
  k_scatter2<<<(E + 255)/256, 256, 0, stream>>>(row, col, cursor_r, eidx,
                                                cursor_c, eidx2, E);
  k_row_fused<<<(N + 3)/4, 256, 0, stream>>>(h, coord, col, Wkv, row_start, eidx,
                                             qn, kn, (const unsigned*)vn, aout,
                                             hout, N);
  // qn/kn dead from here: hn overwrites their region
  k_node_hn<<<(N + 127)/128, 256, 0, stream>>>((const unsigned*)vn, w1f, hn, N);
  k_edge_mlp5<<<2048, 256, 0, stream>>>(coord, row, col, Wr6, Wc2,
                                        (const uint4*)hn, eidx2, mlpout, E);
  k_coord<<<(N + 3)/4, 256, 0, stream>>>(coord, col, row_start, eidx, aout,
                                         mlpout, cout, N);
}